// Round 2
// baseline (301.491 us; speedup 1.0000x reference)
//
#include <hip/hip_runtime.h>
#include <stdint.h>

// ---------------- problem constants ----------------
#define NB   8      // batch
#define SS   2048   // seq
#define DD   1024   // embd
#define BOT  400    // bottleneck
#define BOTP 512    // bottleneck padded to x128 (padded weights = 0 -> h = relu(0) = 0)
#define NAD  25     // adapters
#define LN_EPS 1e-5f

typedef __attribute__((ext_vector_type(8))) short bf8_t;  // 8 bf16 (4 VGPRs)
typedef __attribute__((ext_vector_type(4))) float fx4;

__device__ __forceinline__ unsigned short f2bf(float f) {
  unsigned int u = __float_as_uint(f);
  u = (u + 0x7FFFu + ((u >> 16) & 1u)) >> 16;   // RNE bf16
  return (unsigned short)u;
}

__device__ __forceinline__ void gload16(void* lds, const void* g) {
  __builtin_amdgcn_global_load_lds(
      (const __attribute__((address_space(1))) void*)(uintptr_t)g,
      (__attribute__((address_space(3))) void*)(uint32_t)(uintptr_t)lds,
      16, 0, 0);
}

// ---------------- kernel 1: fused weight-mix + LN partial stats ----------------
// blocks 0..511    : W_down mix -> bf16 [BOTP=512][1024] (rows >=400 zero)
// blocks 512..1023 : W_up   mix -> bf16 [1024][BOTP=512] (cols >=400 zero)
// blocks 1024..1031: wln/bln mix (f32)
// blocks 1032..1543: LN partial sums (8 batches x 64 chunks)
__global__ __launch_bounds__(256) void mixstats_kernel(
    const float* __restrict__ alphas,
    const float* __restrict__ WdAll, const float* __restrict__ WuAll,
    const float* __restrict__ wlnAll, const float* __restrict__ blnAll,
    const float* __restrict__ x,
    unsigned short* __restrict__ Wd, unsigned short* __restrict__ Wu,
    float* __restrict__ wln, float* __restrict__ bln,
    float* __restrict__ partials)
{
  const int tid = threadIdx.x;
  const int bid = blockIdx.x;

  if (bid >= 1032) {                      // ---- stats part ----
    const int g = bid - 1032;
    const int b = g >> 6, c = g & 63;
    const float4* xb = (const float4*)(x + (size_t)b * SS * DD) + (size_t)c * 8192;
    float s = 0.f, q = 0.f;
    for (int i = tid; i < 8192; i += 256) {
      float4 v = xb[i];
      s += v.x + v.y + v.z + v.w;
      q += v.x * v.x + v.y * v.y + v.z * v.z + v.w * v.w;
    }
#pragma unroll
    for (int off = 32; off > 0; off >>= 1) { s += __shfl_down(s, off); q += __shfl_down(q, off); }
    __shared__ float red[8];
    const int wave = tid >> 6, lane = tid & 63;
    if (!lane) { red[wave] = s; red[wave + 4] = q; }
    __syncthreads();
    if (!tid) {
      partials[(b * 64 + c) * 2]     = red[0] + red[1] + red[2] + red[3];
      partials[(b * 64 + c) * 2 + 1] = red[4] + red[5] + red[6] + red[7];
    }
    return;
  }

  __shared__ float a[NAD];
  if (tid < NAD) a[tid] = alphas[tid];
  __syncthreads();

  if (bid < 512) {                        // ---- W_down mix ----
    int g  = bid * 256 + tid;
    int o  = g >> 8;                      // bottleneck row
    int dg = g & 255;                     // float4 group along D
    float4 acc = {0.f, 0.f, 0.f, 0.f};
    if (o < BOT) {
#pragma unroll
      for (int n = 0; n < NAD; ++n) {
        const float4 v = *(const float4*)(WdAll + ((size_t)n * BOT + o) * DD + dg * 4);
        acc.x += a[n] * v.x; acc.y += a[n] * v.y; acc.z += a[n] * v.z; acc.w += a[n] * v.w;
      }
    }
    ushort4 u;
    u.x = f2bf(acc.x); u.y = f2bf(acc.y); u.z = f2bf(acc.z); u.w = f2bf(acc.w);
    *(ushort4*)(Wd + (size_t)o * DD + dg * 4) = u;
  } else if (bid < 1024) {                // ---- W_up mix ----
    int g  = (bid - 512) * 256 + tid;
    int d  = g >> 7;                      // embd row
    int bg = g & 127;                     // float4 group along BOTP
    float4 acc = {0.f, 0.f, 0.f, 0.f};
    if (bg < 100) {
#pragma unroll
      for (int n = 0; n < NAD; ++n) {
        const float4 v = *(const float4*)(WuAll + ((size_t)n * DD + d) * BOT + bg * 4);
        acc.x += a[n] * v.x; acc.y += a[n] * v.y; acc.z += a[n] * v.z; acc.w += a[n] * v.w;
      }
    }
    ushort4 u;
    u.x = f2bf(acc.x); u.y = f2bf(acc.y); u.z = f2bf(acc.z); u.w = f2bf(acc.w);
    *(ushort4*)(Wu + (size_t)d * BOTP + bg * 4) = u;
  } else {                                // ---- wln / bln mix ----
    int i = (bid - 1024) * 256 + tid;
    const float* src = (i < DD) ? wlnAll : blnAll;
    int j = (i < DD) ? i : (i - DD);
    float s = 0.f;
#pragma unroll
    for (int n = 0; n < NAD; ++n) s += a[n] * src[(size_t)n * DD + j];
    if (i < DD) wln[j] = s; else bln[j] = s;
  }
}

// ---------------- kernel 2: normalize -> bf16 x_hat ----------------
__global__ __launch_bounds__(256) void norm_kernel(const float* __restrict__ x,
    const float* __restrict__ partials, const float* __restrict__ wln,
    const float* __restrict__ bln, unsigned short* __restrict__ xn)
{
  const int b = blockIdx.y;
  double s = 0.0, q = 0.0;
#pragma unroll 8
  for (int i = 0; i < 64; ++i) {
    s += partials[(b * 64 + i) * 2];
    q += partials[(b * 64 + i) * 2 + 1];
  }
  const double inv = 1.0 / ((double)SS * DD);
  const float mu  = (float)(s * inv);
  const float var = (float)(q * inv) - mu * mu;
  const float rs  = rsqrtf(var + LN_EPS);

  const size_t base = (size_t)b * SS * DD;
  const int idx = blockIdx.x * 256 + threadIdx.x;
  const float4 v  = *(const float4*)(x + base + (size_t)idx * 4);
  const int dg = idx & 255;
  const float4 w  = *(const float4*)(wln + dg * 4);
  const float4 bb = *(const float4*)(bln + dg * 4);
  ushort4 u;
  u.x = f2bf((v.x - mu) * rs * w.x + bb.x);
  u.y = f2bf((v.y - mu) * rs * w.y + bb.y);
  u.z = f2bf((v.z - mu) * rs * w.z + bb.z);
  u.w = f2bf((v.w - mu) * rs * w.w + bb.w);
  *(ushort4*)(xn + base + (size_t)idx * 4) = u;
}

// ---------------- kernels 3/4: 128x128 MFMA GEMM, C = A[M,K] @ B[N,K]^T ----------------
// Double-buffered prefetch: STAGE(t+1) issued before compute(t); one barrier per K-step.
// RELU=true : relu -> bf16, repacked through LDS -> coalesced int4 stores
// RELU=false: + Xres -> f32 stores
template <int K, int BK, bool RELU>
__global__ __launch_bounds__(256) void gemm_bt(
    const unsigned short* __restrict__ A, const unsigned short* __restrict__ Bm,
    const float* __restrict__ Xres, float* __restrict__ Cf,
    unsigned short* __restrict__ Cb, int N, int nbn)
{
  __shared__ unsigned short As[2][128 * BK];
  __shared__ unsigned short Bs[2][128 * BK];
  const int tid  = threadIdx.x;
  const int wave = tid >> 6, lane = tid & 63;
  const int wr = wave >> 1, wc = wave & 1;

  // bijective XCD swizzle (gridDim.x % 8 == 0 for both launches)
  const int cpx = gridDim.x >> 3;
  const int bid = (blockIdx.x & 7) * cpx + (blockIdx.x >> 3);
  const int bcol = bid % nbn, brow = bid / nbn;
  const unsigned short* Ab = A + (size_t)brow * 128 * K;
  const unsigned short* Bb = Bm + (size_t)bcol * 128 * K;

  constexpr int NL = (128 * BK) / 2048;   // gload rounds per matrix per tile
  auto stage = [&](int buf, int k0) {
#pragma unroll
    for (int i = 0; i < NL; ++i) {
      const int basee = (i * 256 + wave * 64) * 8;    // wave-uniform element base
      const int e   = basee + lane * 8;
      const int row = e / BK, col = e % BK;
      gload16(&As[buf][basee], Ab + (size_t)row * K + k0 + col);
      gload16(&Bs[buf][basee], Bb + (size_t)row * K + k0 + col);
    }
  };

  fx4 acc[4][4] = {};
  constexpr int NT = K / BK;

  stage(0, 0);
  __syncthreads();
  int cur = 0;
  for (int t = 0; t < NT; ++t) {
    if (t + 1 < NT) stage(cur ^ 1, (t + 1) * BK);   // prefetch overlaps compute below
#pragma unroll
    for (int kk = 0; kk < BK / 32; ++kk) {
      bf8_t af[4], bf[4];
#pragma unroll
      for (int m = 0; m < 4; ++m)
        af[m] = *(const bf8_t*)&As[cur][(wr * 64 + m * 16 + (lane & 15)) * BK + kk * 32 + (lane >> 4) * 8];
#pragma unroll
      for (int n = 0; n < 4; ++n)
        bf[n] = *(const bf8_t*)&Bs[cur][(wc * 64 + n * 16 + (lane & 15)) * BK + kk * 32 + (lane >> 4) * 8];
#pragma unroll
      for (int m = 0; m < 4; ++m)
#pragma unroll
        for (int n = 0; n < 4; ++n)
          acc[m][n] = __builtin_amdgcn_mfma_f32_16x16x32_bf16(af[m], bf[n], acc[m][n], 0, 0, 0);
    }
    __syncthreads();   // drains vmcnt (incl. prefetch) + lgkm; next tile ready
    cur ^= 1;
  }

  // epilogue: C/D frag layout col = lane&15, row = (lane>>4)*4 + j (m89-verified)
  if constexpr (RELU) {
    // repack through LDS (reuse As: 2*128*BK*2B >= 32 KB for BK=64) -> coalesced 16B stores
    unsigned short* Hs = (unsigned short*)As;      // [128][128] bf16 = 32 KB
    const int r0l = wr * 64 + ((lane >> 4) << 2);
    const int c0l = wc * 64 + (lane & 15);
#pragma unroll
    for (int m = 0; m < 4; ++m)
#pragma unroll
      for (int n = 0; n < 4; ++n)
#pragma unroll
        for (int j = 0; j < 4; ++j) {
          float v = acc[m][n][j];
          v = v > 0.f ? v : 0.f;
          Hs[(r0l + m * 16 + j) * 128 + (c0l + n * 16)] = f2bf(v);
        }
    __syncthreads();
    const size_t outbase = (size_t)(brow * 128) * N + (size_t)bcol * 128;
#pragma unroll
    for (int i = 0; i < 8; ++i) {
      const int idx = i * 256 + tid;                // 2048 groups of 8 bf16
      const int row = idx >> 4, colg = idx & 15;
      *(int4*)(Cb + outbase + (size_t)row * N + colg * 8) = *(const int4*)&Hs[row * 128 + colg * 8];
    }
  } else {
    const int r0 = brow * 128 + wr * 64 + ((lane >> 4) << 2);
    const int c0 = bcol * 128 + wc * 64 + (lane & 15);
#pragma unroll
    for (int m = 0; m < 4; ++m)
#pragma unroll
      for (int n = 0; n < 4; ++n)
#pragma unroll
        for (int j = 0; j < 4; ++j) {
          const size_t off = (size_t)(r0 + m * 16 + j) * N + (c0 + n * 16);
          Cf[off] = acc[m][n][j] + Xres[off];
        }
  }
}

// ---------------- launcher ----------------
extern "C" void kernel_launch(void* const* d_in, const int* in_sizes, int n_in,
                              void* d_out, int out_size, void* d_ws, size_t ws_size,
                              hipStream_t stream)
{
  const float* x      = (const float*)d_in[0];
  const float* alphas = (const float*)d_in[1];
  const float* WdAll  = (const float*)d_in[2];
  const float* WuAll  = (const float*)d_in[3];
  const float* wlnAll = (const float*)d_in[6];
  const float* blnAll = (const float*)d_in[7];
  float* out = (float*)d_out;

  char* ws = (char*)d_ws;
  unsigned short* Wd  = (unsigned short*)ws;                     // 1 MB
  unsigned short* Wu  = (unsigned short*)(ws + (1u << 20));      // 1 MB
  float* wln          = (float*)(ws + (2u << 20));
  float* bln          = wln + DD;
  float* partials     = bln + DD;                                // 8*64*2 f32
  unsigned short* xn  = (unsigned short*)(ws + (3u << 20));      // 32 MB
  unsigned short* h   = (unsigned short*)(ws + (35u << 20));     // 16 MB

  mixstats_kernel<<<1544, 256, 0, stream>>>(alphas, WdAll, WuAll, wlnAll, blnAll, x,
                                            Wd, Wu, wln, bln, partials);
  norm_kernel<<<dim3(2048, 8), 256, 0, stream>>>(x, partials, wln, bln, xn);
  gemm_bt<1024, 64, true ><<<512,  256, 0, stream>>>(xn, Wd, nullptr, nullptr, h, BOTP, BOTP / 128);
  gemm_bt<512,  32, false><<<1024, 256, 0, stream>>>(h, Wu, x, out, nullptr, DD, DD / 128);
}

// Round 3
// 274.675 us; speedup vs baseline: 1.0976x; 1.0976x over previous
//
#include <hip/hip_runtime.h>
#include <stdint.h>

// ---------------- problem constants ----------------
#define NB   8      // batch
#define SS   2048   // seq
#define DD   1024   // embd
#define BOT  400    // bottleneck
#define BOTP 512    // padded bottleneck (padded weights zeroed -> h pad = relu(0) = 0)
#define NAD  25     // adapters
#define LN_EPS 1e-5f
#define NCH  128    // stats chunks per batch

typedef __attribute__((ext_vector_type(8))) short bf8_t;  // 8 bf16 (4 VGPRs)
typedef __attribute__((ext_vector_type(4))) float fx4;

__device__ __forceinline__ unsigned short f2bf(float f) {
  unsigned int u = __float_as_uint(f);
  u = (u + 0x7FFFu + ((u >> 16) & 1u)) >> 16;   // RNE bf16
  return (unsigned short)u;
}
// packed f32x2 -> bf16x2 (RNE), single instruction
__device__ __forceinline__ uint32_t cvtpk(float lo, float hi) {
  uint32_t r;
  asm("v_cvt_pk_bf16_f32 %0, %1, %2" : "=v"(r) : "v"(lo), "v"(hi));
  return r;
}

__device__ __forceinline__ void gload16(void* lds, const void* g) {
  __builtin_amdgcn_global_load_lds(
      (const __attribute__((address_space(1))) void*)(uintptr_t)g,
      (__attribute__((address_space(3))) void*)(uint32_t)(uintptr_t)lds,
      16, 0, 0);
}

// ---------------- kernel 1: weight mix (high-ILP: 25 loads in flight) ----------------
// blocks [0,400)   : W_down dense mix  (valid region contiguous: 400*1024 f32/adapter)
// blocks [400,800) : W_up   dense mix  (valid region contiguous: 1024*400 f32/adapter)
// blocks [800,808) : wln/bln mix
// blocks [808,864) : zero Wd pad rows 400..511
// blocks [864,920) : zero Wu pad cols 400..511
__global__ __launch_bounds__(256) void mix_kernel(
    const float* __restrict__ alphas,
    const float* __restrict__ WdAll, const float* __restrict__ WuAll,
    const float* __restrict__ wlnAll, const float* __restrict__ blnAll,
    unsigned short* __restrict__ Wd, unsigned short* __restrict__ Wu,
    float* __restrict__ wln, float* __restrict__ bln)
{
  __shared__ float a[NAD];
  const int tid = threadIdx.x;
  if (tid < NAD) a[tid] = alphas[tid];
  __syncthreads();
  const int bid = blockIdx.x;

  if (bid < 800) {                       // dense mixes (identical load shape)
    const int g = (bid < 400 ? bid : bid - 400) * 256 + tid;   // float4-group 0..102399
    const float4* src = (const float4*)(bid < 400 ? WdAll : WuAll) + g;
    float4 vals[NAD];
#pragma unroll
    for (int n = 0; n < NAD; ++n) vals[n] = src[(size_t)n * 102400];  // all in flight
    float4 acc = {0.f, 0.f, 0.f, 0.f};
#pragma unroll
    for (int n = 0; n < NAD; ++n) {
      acc.x += a[n] * vals[n].x; acc.y += a[n] * vals[n].y;
      acc.z += a[n] * vals[n].z; acc.w += a[n] * vals[n].w;
    }
    uint2 pk = { cvtpk(acc.x, acc.y), cvtpk(acc.z, acc.w) };
    if (bid < 400) {
      // Wd [512][1024]: valid region dense -> out elem = 4*g
      *(uint2*)(Wd + (size_t)g * 4) = pk;
    } else {
      // Wu [1024][512]: d = g/100, bg = g%100 -> out elem = d*512 + bg*4
      const int d = g / 100, bg = g - d * 100;
      *(uint2*)(Wu + (size_t)d * BOTP + bg * 4) = pk;
    }
  } else if (bid < 808) {                // wln / bln
    const int i = (bid - 800) * 256 + tid;   // 0..2047
    const float* src = (i < DD) ? wlnAll : blnAll;
    const int j = (i < DD) ? i : (i - DD);
    float v[NAD];
#pragma unroll
    for (int n = 0; n < NAD; ++n) v[n] = src[(size_t)n * DD + j];
    float s = 0.f;
#pragma unroll
    for (int n = 0; n < NAD; ++n) s += a[n] * v[n];
    if (i < DD) wln[j] = s; else bln[j] = s;
  } else if (bid < 864) {                // zero Wd rows 400..511 (contiguous 114688 ushorts)
    const int t = (bid - 808) * 256 + tid;   // 0..14335, ushort8 each
    int4 z = {0, 0, 0, 0};
    *(int4*)(Wd + 400 * 1024 + (size_t)t * 8) = z;
  } else {                               // zero Wu cols 400..511 (112 = 14 x ushort8 per row)
    const int t = (bid - 864) * 256 + tid;   // 0..14335
    const int row = t / 14, c8 = t - row * 14;
    int4 z = {0, 0, 0, 0};
    *(int4*)(Wu + (size_t)row * BOTP + 400 + c8 * 8) = z;
  }
}

// ---------------- kernel 2: LN partial stats ----------------
__global__ __launch_bounds__(256) void stats_kernel(const float* __restrict__ x,
                                                    float* __restrict__ partials)
{
  const int b = blockIdx.y, c = blockIdx.x;  // 8 x 128
  const float4* xb = (const float4*)(x + (size_t)b * SS * DD) + (size_t)c * 4096;
  float s = 0.f, q = 0.f;
#pragma unroll 4
  for (int i = threadIdx.x; i < 4096; i += 256) {
    float4 v = xb[i];
    s += v.x + v.y + v.z + v.w;
    q += v.x * v.x + v.y * v.y + v.z * v.z + v.w * v.w;
  }
#pragma unroll
  for (int off = 32; off > 0; off >>= 1) { s += __shfl_down(s, off); q += __shfl_down(q, off); }
  __shared__ float red[8];
  const int wave = threadIdx.x >> 6, lane = threadIdx.x & 63;
  if (!lane) { red[wave] = s; red[wave + 4] = q; }
  __syncthreads();
  if (!threadIdx.x) {
    partials[(b * NCH + c) * 2]     = red[0] + red[1] + red[2] + red[3];
    partials[(b * NCH + c) * 2 + 1] = red[4] + red[5] + red[6] + red[7];
  }
}

// ---------------- kernel 3: GEMM1 with fused normalize ----------------
// H[16384][512] = relu( LN(x)[16384][1024] @ Wd[512][1024]^T ), bf16 out.
// A reg-staged (normalize on the fly, swizzled ds_write); B via pre-swizzled gload_lds.
// LDS XOR swizzle (BK=64, 128B rows): byte ^= (row&7)<<4  -> frag reads ~2-way (free).
__global__ __launch_bounds__(256) void gemm1(
    const float* __restrict__ x, const unsigned short* __restrict__ Bw,
    const float* __restrict__ partials, const float* __restrict__ wln,
    const float* __restrict__ bln, unsigned short* __restrict__ H)
{
  __shared__ unsigned short As[2][128 * 64];   // 16 KB each
  __shared__ unsigned short Bs[2][128 * 64];
  __shared__ float s1[DD], s2[DD];             // per-column affine: x*s1+s2
  const int tid = threadIdx.x, wave = tid >> 6, lane = tid & 63;
  const int wr = wave >> 1, wc = wave & 1;
  // chunked XCD swizzle: same-XCD blocks get contiguous orig ids (share A-panels in L2)
  const int bid = (blockIdx.x & 7) * 64 + (blockIdx.x >> 3);   // grid 512
  const int bcol = bid & 3, brow = bid >> 2;
  const int b = brow >> 4;                     // batch (16 M-tiles per batch)

  double sd = 0.0, qd = 0.0;
#pragma unroll 8
  for (int i = 0; i < NCH; ++i) {
    sd += partials[(b * NCH + i) * 2];
    qd += partials[(b * NCH + i) * 2 + 1];
  }
  const float mu  = (float)(sd * (1.0 / 2097152.0));
  const float var = (float)(qd * (1.0 / 2097152.0)) - mu * mu;
  const float rs  = rsqrtf(var + LN_EPS);
  for (int c = tid; c < DD; c += 256) {
    const float v1 = rs * wln[c];
    s1[c] = v1; s2[c] = bln[c] - mu * v1;
  }

  const float* Ab = x + (size_t)(brow * 128) * DD;
  const unsigned short* Bb = Bw + (size_t)(bcol * 128) * DD;
  const int arow = tid >> 3;            // 0..31 (+32/round)
  const int c8   = tid & 7;             // col-octet within BK=64
  const int aswz = (arow & 7) << 4;     // row-invariant across rounds (32 | 8)

  // issue 8 x-loads (independent, stay in flight through compute)
  auto loadA = [&](int k0, float4* xr) {
#pragma unroll
    for (int i = 0; i < 4; ++i) {
      const float* p = Ab + (size_t)(i * 32 + arow) * DD + k0 + c8 * 8;
      xr[i * 2]     = *(const float4*)p;
      xr[i * 2 + 1] = *(const float4*)(p + 4);
    }
  };
  // normalize + cvt + swizzled ds_write
  auto writeA = [&](int buf, int k0, const float4* xr) {
    const float4 w0 = *(const float4*)&s1[k0 + c8 * 8];
    const float4 w1 = *(const float4*)&s1[k0 + c8 * 8 + 4];
    const float4 b0 = *(const float4*)&s2[k0 + c8 * 8];
    const float4 b1 = *(const float4*)&s2[k0 + c8 * 8 + 4];
#pragma unroll
    for (int i = 0; i < 4; ++i) {
      const float4 v0 = xr[i * 2], v1 = xr[i * 2 + 1];
      uint4 pk;
      pk.x = cvtpk(v0.x * w0.x + b0.x, v0.y * w0.y + b0.y);
      pk.y = cvtpk(v0.z * w0.z + b0.z, v0.w * w0.w + b0.w);
      pk.z = cvtpk(v1.x * w1.x + b1.x, v1.y * w1.y + b1.y);
      pk.w = cvtpk(v1.z * w1.z + b1.z, v1.w * w1.w + b1.w);
      *(uint4*)((char*)&As[buf][0] + (i * 32 + arow) * 128 + ((c8 * 16) ^ aswz)) = pk;
    }
  };
  // B: gload_lds with pre-swizzled global source (linear LDS dest, m173 pattern)
  auto stageB = [&](int buf, int k0) {
#pragma unroll
    for (int i = 0; i < 4; ++i) {
      const int q   = i * 256 + wave * 64;          // wave-uniform octet base
      const int ql  = q + lane;
      const int row = ql >> 3, c16 = ql & 7;
      const int o   = c16 ^ (row & 7);
      gload16(&Bs[buf][q * 8], Bb + (size_t)row * DD + k0 + o * 8);
    }
  };

  fx4 acc[4][4] = {};
  auto compute = [&](int buf) {
#pragma unroll
    for (int kk = 0; kk < 2; ++kk) {
      bf8_t af[4], bf[4];
#pragma unroll
      for (int m = 0; m < 4; ++m) {
        const int r = wr * 64 + m * 16 + (lane & 15);
        af[m] = *(const bf8_t*)((const char*)&As[buf][0] + r * 128 +
                                ((kk * 64 + (lane >> 4) * 16) ^ ((r & 7) << 4)));
      }
#pragma unroll
      for (int n = 0; n < 4; ++n) {
        const int r = wc * 64 + n * 16 + (lane & 15);
        bf[n] = *(const bf8_t*)((const char*)&Bs[buf][0] + r * 128 +
                                ((kk * 64 + (lane >> 4) * 16) ^ ((r & 7) << 4)));
      }
#pragma unroll
      for (int m = 0; m < 4; ++m)
#pragma unroll
        for (int n = 0; n < 4; ++n)
          acc[m][n] = __builtin_amdgcn_mfma_f32_16x16x32_bf16(af[m], bf[n], acc[m][n], 0, 0, 0);
    }
  };

  float4 xrA[8], xrB[8];                 // named (static-indexed) — no scratch
  loadA(0, xrA); stageB(0, 0);
  __syncthreads();                       // s1/s2 visible
  writeA(0, 0, xrA);
  __syncthreads();                       // buffers 0 ready (drains vmcnt+lgkm)
#pragma unroll 1
  for (int t2 = 0; t2 < 8; ++t2) {
    {
      const int t = t2 * 2;
      if (t < 15) { loadA((t + 1) * 64, xrB); stageB(1, (t + 1) * 64); }
      compute(0);
      if (t < 15) writeA(1, (t + 1) * 64, xrB);
      __syncthreads();
    }
    {
      const int t = t2 * 2 + 1;
      if (t < 15) { loadA((t + 1) * 64, xrA); stageB(0, (t + 1) * 64); }
      compute(1);
      if (t < 15) writeA(0, (t + 1) * 64, xrA);
      __syncthreads();
    }
  }

  // epilogue: relu -> bf16 repack through LDS (reuse As: 32KB) -> coalesced int4 stores
  unsigned short* Hs = &As[0][0];        // [128][128]
  const int r0l = wr * 64 + ((lane >> 4) << 2);
  const int c0l = wc * 64 + (lane & 15);
#pragma unroll
  for (int m = 0; m < 4; ++m)
#pragma unroll
    for (int n = 0; n < 4; ++n)
#pragma unroll
      for (int j = 0; j < 4; ++j) {
        float v = acc[m][n][j];
        Hs[(r0l + m * 16 + j) * 128 + (c0l + n * 16)] = f2bf(v > 0.f ? v : 0.f);
      }
  __syncthreads();
  const size_t outbase = (size_t)(brow * 128) * BOTP + (size_t)bcol * 128;
#pragma unroll
  for (int i = 0; i < 8; ++i) {
    const int idx = i * 256 + tid;
    const int row = idx >> 4, colg = idx & 15;
    *(int4*)(H + outbase + (size_t)row * BOTP + colg * 8) = *(const int4*)&Hs[row * 128 + colg * 8];
  }
}

// ---------------- kernel 4: GEMM2 + residual ----------------
// out[16384][1024] = x + H[16384][512] @ Wu[1024][512]^T, f32 out.
// Both operands gload_lds with pre-swizzled source; BK=32 (64B rows): byte ^= (row&3)<<4.
__global__ __launch_bounds__(256) void gemm2(
    const unsigned short* __restrict__ A, const unsigned short* __restrict__ Bm,
    const float* __restrict__ Xres, float* __restrict__ out)
{
  __shared__ unsigned short As[2][128 * 32];   // 8 KB each
  __shared__ unsigned short Bs[2][128 * 32];
  const int tid = threadIdx.x, wave = tid >> 6, lane = tid & 63;
  const int wr = wave >> 1, wc = wave & 1;
  const int bid = (blockIdx.x & 7) * 128 + (blockIdx.x >> 3);   // grid 1024
  const int bcol = bid & 7, brow = bid >> 3;
  const unsigned short* Ab = A + (size_t)(brow * 128) * BOTP;
  const unsigned short* Bb = Bm + (size_t)(bcol * 128) * BOTP;

  auto stage = [&](int buf, int k0) {
#pragma unroll
    for (int i = 0; i < 2; ++i) {
      const int q   = i * 256 + wave * 64;
      const int ql  = q + lane;
      const int row = ql >> 2, c16 = ql & 3;
      const int o   = c16 ^ (row & 3);
      gload16(&As[buf][q * 8], Ab + (size_t)row * BOTP + k0 + o * 8);
      gload16(&Bs[buf][q * 8], Bb + (size_t)row * BOTP + k0 + o * 8);
    }
  };

  fx4 acc[4][4] = {};
  stage(0, 0);
  __syncthreads();
  for (int t = 0; t < 16; ++t) {
    const int cur = t & 1;
    if (t < 15) stage(cur ^ 1, (t + 1) * 32);
    bf8_t af[4], bf[4];
    const int hi16 = (lane >> 4) * 16;
#pragma unroll
    for (int m = 0; m < 4; ++m) {
      const int r = wr * 64 + m * 16 + (lane & 15);
      af[m] = *(const bf8_t*)((const char*)&As[cur][0] + r * 64 + (hi16 ^ ((r & 3) << 4)));
    }
#pragma unroll
    for (int n = 0; n < 4; ++n) {
      const int r = wc * 64 + n * 16 + (lane & 15);
      bf[n] = *(const bf8_t*)((const char*)&Bs[cur][0] + r * 64 + (hi16 ^ ((r & 3) << 4)));
    }
#pragma unroll
    for (int m = 0; m < 4; ++m)
#pragma unroll
      for (int n = 0; n < 4; ++n)
        acc[m][n] = __builtin_amdgcn_mfma_f32_16x16x32_bf16(af[m], bf[n], acc[m][n], 0, 0, 0);
    __syncthreads();
  }

  const int r0 = brow * 128 + wr * 64 + ((lane >> 4) << 2);
  const int c0 = bcol * 128 + wc * 64 + (lane & 15);
#pragma unroll
  for (int m = 0; m < 4; ++m)
#pragma unroll
    for (int n = 0; n < 4; ++n)
#pragma unroll
      for (int j = 0; j < 4; ++j) {
        const size_t off = (size_t)(r0 + m * 16 + j) * DD + (c0 + n * 16);
        out[off] = acc[m][n][j] + Xres[off];
      }
}

// ---------------- launcher ----------------
extern "C" void kernel_launch(void* const* d_in, const int* in_sizes, int n_in,
                              void* d_out, int out_size, void* d_ws, size_t ws_size,
                              hipStream_t stream)
{
  const float* x      = (const float*)d_in[0];
  const float* alphas = (const float*)d_in[1];
  const float* WdAll  = (const float*)d_in[2];
  const float* WuAll  = (const float*)d_in[3];
  const float* wlnAll = (const float*)d_in[6];
  const float* blnAll = (const float*)d_in[7];
  float* out = (float*)d_out;

  char* ws = (char*)d_ws;
  unsigned short* Wd  = (unsigned short*)ws;                  // [512][1024] bf16, 1 MB
  unsigned short* Wu  = (unsigned short*)(ws + (1u << 20));   // [1024][512] bf16, 1 MB
  float* wln          = (float*)(ws + (2u << 20));
  float* bln          = wln + DD;
  float* partials     = bln + DD;                             // 8*128*2 f32
  unsigned short* h   = (unsigned short*)(ws + (3u << 20));   // [16384][512] bf16, 16 MB

  mix_kernel<<<920, 256, 0, stream>>>(alphas, WdAll, WuAll, wlnAll, blnAll, Wd, Wu, wln, bln);
  stats_kernel<<<dim3(NCH, NB), 256, 0, stream>>>(x, partials);
  gemm1<<<512, 256, 0, stream>>>(x, Wd, partials, wln, bln, h);
  gemm2<<<1024, 256, 0, stream>>>(h, Wu, x, out);
}